// Round 13
// baseline (143.755 us; speedup 1.0000x reference)
//
#include <hip/hip_runtime.h>
#include <hip/hip_bf16.h>

#define B_    4
#define C_    64
#define H_    192
#define W_    192
#define TAPS_ 9
#define MID_  12
#define HW_   (H_ * W_)
#define K_TOT 576                      // C_ * TAPS_
#define AT_STRIDE 72                   // bf16 elems per a_T row (8 chunks data + 1 pad chunk)

constexpr float STD_ = 0.47140452079103173f;  // sqrt(2)/3

using bf16 = __hip_bfloat16;
typedef __attribute__((ext_vector_type(4))) float  f32x4;
typedef __attribute__((ext_vector_type(8))) short  short8;

__device__ __forceinline__ unsigned short f2bf_bits(float v) {
    union { bf16 h; unsigned short u; } cv;
    cv.h = __float2bfloat16(v);   // RNE
    return cv.u;
}

// aT XOR swizzle: 16-B chunks within a row permuted by key=(row>>2)&7.
// Word-granular address (cw = word col 0..31; data only, pad chunk 8 untouched).
__device__ __forceinline__ int at_word(int row, int cw) {
    int key = (row >> 2) & 7;
    return row * (AT_STRIDE / 2) + ((((cw >> 2) ^ key) & 7) << 2) + (cw & 3);
}

// ---------------------------------------------------------------------------
// k_pre: fused {w2 repack -> bf16 [o][t*64+c]} (blocks 0..143) and
//        {x row partial sums} (blocks 144..911).
// ---------------------------------------------------------------------------
__global__ __launch_bounds__(256) void k_pre(const float* __restrict__ x,
                                             const float* __restrict__ w2,
                                             unsigned short* __restrict__ w2bf,
                                             float* __restrict__ partials) {
    int bx = blockIdx.x;
    if (bx < 144) {
        int d = bx * 256 + threadIdx.x;          // dest index, 36864 total
        int o = d / K_TOT;
        int rem = d - o * K_TOT;
        int t = rem >> 6;
        int c = rem & 63;
        w2bf[d] = f2bf_bits(w2[(o * C_ + c) * TAPS_ + t]);
        return;
    }
    bx -= 144;
    int bc = bx / 3, part = bx - 3 * (bx / 3);
    const float4* p = (const float4*)(x + (size_t)bc * HW_ + part * 12288);
    float s = 0.f;
    #pragma unroll
    for (int k = 0; k < 12; ++k) {
        float4 u = p[threadIdx.x + k * 256];
        s += u.x + u.y + u.z + u.w;
    }
    #pragma unroll
    for (int off = 32; off; off >>= 1) s += __shfl_down(s, off);
    __shared__ float red[4];
    if ((threadIdx.x & 63) == 0) red[threadIdx.x >> 6] = s;
    __syncthreads();
    if (threadIdx.x == 0)
        partials[bx] = red[0] + red[1] + red[2] + red[3];
}

// ---------------------------------------------------------------------------
// k_main: one block per (b,h) row. 256 thr / 4 waves. cf-branch folded into
// wave 3 of phase A (R5); XCD-chunked swizzle (R6); shuffle edges (R7);
// hand-forced MLP (R10: 56.5->48.9us).
// R13: the persistent 5.4MB scratch spill (R10-R12, WRITE 42.2 vs 36.9MB)
// is the allocator pinning VGPR=84 (the 6-waves/SIMD boundary) and spilling
// ~7 dwords/thread -- occupancy headroom the 768-block grid can never use
// (3 blocks/CU by grid; 4 by LDS). Drop the min-waves hint: __launch_bounds__
// (256) lets the allocator take the ~95-110 regs the kernel actually needs;
// any count <=170 keeps the required 3 waves/SIMD.
//   A: spatial filters, 8+8 double-buffered load batches + sched_barrier
//   B: wave<->16ch, lane<->4 px; named 6xfloat4 prefetch one pair ahead
//      (iter-0 loads hoisted before A); halo rows branch-free via x{0,1};
//      writes a_T bf16 with XOR-chunk swizzle
//   C: 1x9 conv as bf16 MFMA GEMM M=64 x N=192 x K=576; A-frags streamed
//      through a rolling 3-register window, distance-2 prefetch
// ---------------------------------------------------------------------------
__global__ __launch_bounds__(256) void k_main(const float* __restrict__ x,
                                              const float* __restrict__ sw,
                                              const float* __restrict__ sb,
                                              const float* __restrict__ partials,
                                              const float* __restrict__ cw1,
                                              const float* __restrict__ cb1,
                                              const float* __restrict__ cw2,
                                              const float* __restrict__ cb2,
                                              const unsigned short* __restrict__ w2bf,
                                              const float* __restrict__ bias2,
                                              float* __restrict__ out) {
    __shared__ __align__(16) char smem[38624];
    short*          aT    = (short*)smem;           // 200*72*2 = 28800 B
    unsigned*       aT32  = (unsigned*)smem;
    float*          sw_l  = (float*)smem;           // alias (phase A only), 2304 B
    float*          s_l   = (float*)(smem + 28800); // 4*9*48*4 = 6912 B
    float*          b2_l  = (float*)(smem + 35712); // 256 B
    float*          sb_l  = (float*)(smem + 35968); // 40 B
    float*          cfn_l = (float*)(smem + 36016); // 64*9*4 = 2304 B
    float*          h1_l  = (float*)(smem + 38320); // 48 B
    float*          g_l   = (float*)(smem + 38368); // 256 B

    int bx = blockIdx.x;
    int bh = (bx & 7) * 96 + (bx >> 3);   // XCD-chunked swizzle (768 = 8*96)
    int bb = bh / H_;
    int h  = bh - bb * H_;
    int tid = threadIdx.x;
    int lane = tid & 63, wid = tid >> 6;
    int quad = lane >> 4, l16 = lane & 15;
    int obase = wid * 16;
    int w0 = 4 * lane;                    // phase-B pixel base (lane<48 only)

    // ---- stage small tables ----
    for (int i = tid; i < TAPS_ * C_; i += 256) sw_l[i] = sw[i];
    if (tid < C_) b2_l[tid] = bias2[tid];
    if (tid < TAPS_) sb_l[tid] = sb[tid];
    __syncthreads();

    // ---- preload first 2 A-fragments (8 VGPRs, in flight across A+B) ----
    const short* w2s = (const short*)w2bf;
    const short* arow = w2s + (obase + l16) * K_TOT + quad * 8;
    short8 a0 = *(const short8*)(arow);
    short8 a1 = *(const short8*)(arow + 32);

    // ---- phase-B row offsets (clamped halo; zeroed via rokf scale) ----
    long ro0 = (long)((h > 0) ? (h - 1) : h) * W_;
    long ro1 = (long)h * W_;
    long ro2 = (long)((h < H_ - 1) ? (h + 1) : h) * W_;
    const float* xc = x + (size_t)bb * C_ * HW_;

    // ---- phase-B iteration-0 prologue loads: issued BEFORE phase A so the
    //      L2/HBM latency hides under phase A compute (R10: works; R11 showed
    //      loading them inside B spills B's hot loop instead -- worse). ----
    float4 P0a, P1a, P2a, P0b, P1b, P2b;
    if (lane < 48) {
        const float* q0 = xc + (size_t)(wid * 16) * HW_;
        const float* q1 = q0 + HW_;
        P0a = *(const float4*)(q0 + ro0 + w0);
        P1a = *(const float4*)(q0 + ro1 + w0);
        P2a = *(const float4*)(q0 + ro2 + w0);
        P0b = *(const float4*)(q1 + ro0 + w0);
        P1b = *(const float4*)(q1 + ro1 + w0);
        P2b = *(const float4*)(q1 + ro2 + w0);
    }

    // ---- Phase A: spatial filters (waves 0..2, 8+8 double-buffered loads) ∥
    //      channel branch (wave 3) ----
    if (tid < W_) {
        int w = tid;
        float acc[TAPS_];
        #pragma unroll
        for (int t = 0; t < TAPS_; ++t) acc[t] = sb_l[t];
        const float* px = x + (size_t)bb * C_ * HW_ + h * W_ + w;
        float xv0[8], xv1[8];
        #pragma unroll
        for (int j = 0; j < 8; ++j) xv0[j] = px[(size_t)j * HW_];
        #pragma unroll
        for (int j = 0; j < 8; ++j) xv1[j] = px[(size_t)(8 + j) * HW_];
        __builtin_amdgcn_sched_barrier(0);

#define FMA8(XV, CB)                                                           \
        do {                                                                   \
            _Pragma("unroll")                                                  \
            for (int j = 0; j < 8; ++j)                                        \
                _Pragma("unroll")                                              \
                for (int t = 0; t < TAPS_; ++t)                                \
                    acc[t] = fmaf(XV[j], sw_l[t * C_ + (CB) + j], acc[t]);     \
        } while (0)
#define LOAD8(XV, CB)                                                          \
        do {                                                                   \
            _Pragma("unroll")                                                  \
            for (int j = 0; j < 8; ++j) XV[j] = px[(size_t)((CB) + j) * HW_];  \
        } while (0)

        FMA8(xv0, 0);   LOAD8(xv0, 16); __builtin_amdgcn_sched_barrier(0);
        FMA8(xv1, 8);   LOAD8(xv1, 24); __builtin_amdgcn_sched_barrier(0);
        FMA8(xv0, 16);  LOAD8(xv0, 32); __builtin_amdgcn_sched_barrier(0);
        FMA8(xv1, 24);  LOAD8(xv1, 40); __builtin_amdgcn_sched_barrier(0);
        FMA8(xv0, 32);  LOAD8(xv0, 48); __builtin_amdgcn_sched_barrier(0);
        FMA8(xv1, 40);  LOAD8(xv1, 56); __builtin_amdgcn_sched_barrier(0);
        FMA8(xv0, 48);
        FMA8(xv1, 56);
#undef FMA8
#undef LOAD8

        float mean = 0.f;
        #pragma unroll
        for (int t = 0; t < TAPS_; ++t) mean += acc[t];
        mean *= (1.f / TAPS_);
        float var = 0.f;
        #pragma unroll
        for (int t = 0; t < TAPS_; ++t) { float d = acc[t] - mean; var += d * d; }
        var *= (1.f / (TAPS_ - 1));
        float scale = STD_ / (sqrtf(fmaxf(var, 0.f)) + 1e-10f);
        float* sp = s_l + (w & 3) * 432 + (w >> 2);
        #pragma unroll
        for (int t = 0; t < TAPS_; ++t) sp[t * 48] = (acc[t] - mean) * scale;
    } else {
        // wave 3, lane = channel c. All LDS chains below are same-array
        // write->read in one lockstep wave (compiler orders via lgkmcnt).
        int c = lane;
        const float* pp = partials + (bb * C_ + c) * 3;
        g_l[c] = (pp[0] + pp[1] + pp[2]) * (1.0f / HW_);
        if (c < MID_) {
            float acc = cb1[c];
            #pragma unroll 8
            for (int cc = 0; cc < C_; ++cc) acc += g_l[cc] * cw1[c * C_ + cc];
            h1_l[c] = fmaxf(acc, 0.f);
        }
        float f[TAPS_];
        float mean = 0.f;
        #pragma unroll
        for (int t = 0; t < TAPS_; ++t) {
            int n = c * TAPS_ + t;
            float acc = cb2[n];
            #pragma unroll
            for (int m = 0; m < MID_; ++m) acc += h1_l[m] * cw2[n * MID_ + m];
            f[t] = acc;
            mean += acc;
        }
        mean *= (1.f / TAPS_);
        float var = 0.f;
        #pragma unroll
        for (int t = 0; t < TAPS_; ++t) { float d = f[t] - mean; var += d * d; }
        var *= (1.f / (TAPS_ - 1));
        float scale = STD_ / (sqrtf(fmaxf(var, 0.f)) + 1e-10f);
        #pragma unroll
        for (int t = 0; t < TAPS_; ++t)
            cfn_l[c * TAPS_ + t] = (f[t] - mean) * scale;
    }
    __syncthreads();   // phase B overwrites sw_l alias (aT); reads s_l + cfn_l

    // ---- zero a_T halo rows (0..3 and 196..199); swizzle is a row-local
    //      permutation, so linear zeroing covers exactly the same words ----
    for (int i = tid; i < 8 * (AT_STRIDE / 2); i += 256) {
        int rowIdx = i / (AT_STRIDE / 2);
        int col    = i - rowIdx * (AT_STRIDE / 2);
        int r = (rowIdx < 4) ? rowIdx : (192 + rowIdx);
        aT32[r * (AT_STRIDE / 2) + col] = 0u;
    }

    // ---- Phase B: DDF apply + leaky -> a_T bf16 (swizzled), pipelined ----
    {
        if (lane < 48) {
            float sreg[4][TAPS_];      // conflict-free: word = 432k+48t+lane
            #pragma unroll
            for (int k = 0; k < 4; ++k) {
                const float* sp = s_l + k * 432 + lane;
                #pragma unroll
                for (int t = 0; t < TAPS_; ++t) sreg[k][t] = sp[t * 48];
            }
            bool l0 = (lane == 0), l47 = (lane == 47);
            float rok0f = (h > 0)      ? 1.f : 0.f;
            float rok2f = (h < H_ - 1) ? 1.f : 0.f;

#define TAPROW(RR, FA, FB)                                                     \
            do {                                                               \
                float ma = __shfl_up(FA.w, 1);   ma = l0  ? 0.f : ma;          \
                float mb = __shfl_up(FB.w, 1);   mb = l0  ? 0.f : mb;          \
                float pa = __shfl_down(FA.x, 1); pa = l47 ? 0.f : pa;          \
                float pb = __shfl_down(FB.x, 1); pb = l47 ? 0.f : pb;          \
                float va[6] = { ma, FA.x, FA.y, FA.z, FA.w, pa };              \
                float vb[6] = { mb, FB.x, FB.y, FB.z, FB.w, pb };              \
                _Pragma("unroll")                                              \
                for (int dc = 0; dc < 3; ++dc) {                               \
                    int t = (RR) * 3 + dc;                                     \
                    float cva = cfp[t];                                        \
                    float cvb = cfp[TAPS_ + t];                                \
                    _Pragma("unroll")                                          \
                    for (int k = 0; k < 4; ++k) {                              \
                        acc0[k] = fmaf(va[k + dc] * sreg[k][t], cva, acc0[k]); \
                        acc1[k] = fmaf(vb[k + dc] * sreg[k][t], cvb, acc1[k]); \
                    }                                                          \
                }                                                              \
            } while (0)

            #pragma unroll 1
            for (int i = 0; i < 16; i += 2) {
                int c0 = wid * 16 + i;
                int cu = __builtin_amdgcn_readfirstlane(c0);
                const float* cfp = cfn_l + cu * TAPS_;   // LDS broadcast
                // consume current prefetch
                float4 C0a = P0a, C1a = P1a, C2a = P2a;
                float4 C0b = P0b, C1b = P1b, C2b = P2b;
                // prefetch next channel pair (distance 1)
                if (i < 14) {
                    const float* q0 = xc + (size_t)(c0 + 2) * HW_;
                    const float* q1 = q0 + HW_;
                    P0a = *(const float4*)(q0 + ro0 + w0);
                    P1a = *(const float4*)(q0 + ro1 + w0);
                    P2a = *(const float4*)(q0 + ro2 + w0);
                    P0b = *(const float4*)(q1 + ro0 + w0);
                    P1b = *(const float4*)(q1 + ro1 + w0);
                    P2b = *(const float4*)(q1 + ro2 + w0);
                }
                __builtin_amdgcn_sched_barrier(0);
                // zero halo-row contributions (exact: 0 * finite == 0 == pad)
                C0a.x *= rok0f; C0a.y *= rok0f; C0a.z *= rok0f; C0a.w *= rok0f;
                C0b.x *= rok0f; C0b.y *= rok0f; C0b.z *= rok0f; C0b.w *= rok0f;
                C2a.x *= rok2f; C2a.y *= rok2f; C2a.z *= rok2f; C2a.w *= rok2f;
                C2b.x *= rok2f; C2b.y *= rok2f; C2b.z *= rok2f; C2b.w *= rok2f;
                float acc0[4] = {0.f, 0.f, 0.f, 0.f};
                float acc1[4] = {0.f, 0.f, 0.f, 0.f};
                TAPROW(0, C0a, C0b);
                TAPROW(1, C1a, C1b);
                TAPROW(2, C2a, C2b);
                int cw = c0 >> 1;                  // word col 0..31
                #pragma unroll
                for (int k = 0; k < 4; ++k) {
                    float a0v = acc0[k]; a0v = (a0v >= 0.f) ? a0v : 0.1f * a0v;
                    float a1v = acc1[k]; a1v = (a1v >= 0.f) ? a1v : 0.1f * a1v;
                    unsigned pk = (unsigned)f2bf_bits(a0v)
                                | ((unsigned)f2bf_bits(a1v) << 16);
                    aT32[at_word(w0 + k + 4, cw)] = pk;
                }
            }
#undef TAPROW
        }
    }
    __syncthreads();

    // ---- Phase C: MFMA GEMM out[o][w] += A[o][q] * B[q][w], q = t*64 + c ----
    {
        f32x4 acc[12];
        #pragma unroll
        for (int n = 0; n < 12; ++n) acc[n] = (f32x4){0.f, 0.f, 0.f, 0.f};

        #pragma unroll 1
        for (int kk = 0; kk < 18; ++kk) {
            short8 a2 = a1;
            if (kk < 16) a2 = *(const short8*)(arow + (kk + 2) * 32);  // dist-2 stream
            int t = kk >> 1;
            int ch = ((kk & 1) << 2) + quad;     // 16-B chunk index 0..7
            int rowb = l16 + t;
            int key0 = (rowb >> 2) & 7;          // key(n) = key0 ^ (4*(n&1))
            int off0 = rowb * AT_STRIDE + (((ch ^ key0) & 7) << 3);
            int off1 = rowb * AT_STRIDE + (((ch ^ key0 ^ 4) & 7) << 3);
            #pragma unroll
            for (int n = 0; n < 12; ++n) {
                int off = ((n & 1) ? off1 : off0) + n * 16 * AT_STRIDE;
                short8 bf = *(const short8*)(aT + off);
                acc[n] = __builtin_amdgcn_mfma_f32_16x16x32_bf16(a0, bf, acc[n], 0, 0, 0);
            }
            a0 = a1; a1 = a2;
        }

        // epilogue: bias + residual add, C/D layout col=lane&15, row=quad*4+reg
        size_t xbase = (size_t)bb * C_ * HW_ + (size_t)h * W_;
        #pragma unroll
        for (int n = 0; n < 12; ++n) {
            int w = n * 16 + l16;
            #pragma unroll
            for (int reg = 0; reg < 4; ++reg) {
                int o = obase + quad * 4 + reg;
                size_t idx = xbase + (size_t)o * HW_ + w;
                out[idx] = acc[n][reg] + b2_l[o] + x[idx];
            }
        }
    }
}

// ---------------------------------------------------------------------------
extern "C" void kernel_launch(void* const* d_in, const int* in_sizes, int n_in,
                              void* d_out, int out_size, void* d_ws, size_t ws_size,
                              hipStream_t stream) {
    const float* x   = (const float*)d_in[0];
    const float* sw  = (const float*)d_in[1];
    const float* sb  = (const float*)d_in[2];
    const float* cw1 = (const float*)d_in[3];
    const float* cb1 = (const float*)d_in[4];
    const float* cw2 = (const float*)d_in[5];
    const float* cb2 = (const float*)d_in[6];
    const float* w2  = (const float*)d_in[7];
    const float* b2  = (const float*)d_in[8];
    float* out = (float*)d_out;

    unsigned short* w2bf = (unsigned short*)d_ws;                 // 73728 B
    float* partials = (float*)((char*)d_ws + 73728);              // 3072 B

    hipLaunchKernelGGL(k_pre, dim3(912), dim3(256), 0, stream, x, w2, w2bf, partials);
    hipLaunchKernelGGL(k_main, dim3(B_ * H_), dim3(256), 0, stream,
                       x, sw, sb, partials, cw1, cb1, cw2, cb2, w2bf, b2, out);
}

// Round 14
// 134.293 us; speedup vs baseline: 1.0705x; 1.0705x over previous
//
#include <hip/hip_runtime.h>
#include <hip/hip_bf16.h>

#define B_    4
#define C_    64
#define H_    192
#define W_    192
#define TAPS_ 9
#define MID_  12
#define HW_   (H_ * W_)
#define K_TOT 576                      // C_ * TAPS_
#define AT_STRIDE 72                   // bf16 elems per a_T row (8 chunks data + 1 pad chunk)

constexpr float STD_ = 0.47140452079103173f;  // sqrt(2)/3

using bf16 = __hip_bfloat16;
typedef __attribute__((ext_vector_type(4))) float  f32x4;
typedef __attribute__((ext_vector_type(8))) short  short8;

__device__ __forceinline__ unsigned short f2bf_bits(float v) {
    union { bf16 h; unsigned short u; } cv;
    cv.h = __float2bfloat16(v);   // RNE
    return cv.u;
}

// aT XOR swizzle: 16-B chunks within a row permuted by key=(row>>2)&7.
// Word-granular address (cw = word col 0..31; data only, pad chunk 8 untouched).
__device__ __forceinline__ int at_word(int row, int cw) {
    int key = (row >> 2) & 7;
    return row * (AT_STRIDE / 2) + ((((cw >> 2) ^ key) & 7) << 2) + (cw & 3);
}

// ---------------------------------------------------------------------------
// k_pre: fused {w2 repack -> bf16 [o][t*64+c]} (blocks 0..143) and
//        {x row partial sums} (blocks 144..911).
// ---------------------------------------------------------------------------
__global__ __launch_bounds__(256) void k_pre(const float* __restrict__ x,
                                             const float* __restrict__ w2,
                                             unsigned short* __restrict__ w2bf,
                                             float* __restrict__ partials) {
    int bx = blockIdx.x;
    if (bx < 144) {
        int d = bx * 256 + threadIdx.x;          // dest index, 36864 total
        int o = d / K_TOT;
        int rem = d - o * K_TOT;
        int t = rem >> 6;
        int c = rem & 63;
        w2bf[d] = f2bf_bits(w2[(o * C_ + c) * TAPS_ + t]);
        return;
    }
    bx -= 144;
    int bc = bx / 3, part = bx - 3 * (bx / 3);
    const float4* p = (const float4*)(x + (size_t)bc * HW_ + part * 12288);
    float s = 0.f;
    #pragma unroll
    for (int k = 0; k < 12; ++k) {
        float4 u = p[threadIdx.x + k * 256];
        s += u.x + u.y + u.z + u.w;
    }
    #pragma unroll
    for (int off = 32; off; off >>= 1) s += __shfl_down(s, off);
    __shared__ float red[4];
    if ((threadIdx.x & 63) == 0) red[threadIdx.x >> 6] = s;
    __syncthreads();
    if (threadIdx.x == 0)
        partials[bx] = red[0] + red[1] + red[2] + red[3];
}

// ---------------------------------------------------------------------------
// k_main: one block per (b,h) row. 256 thr / 4 waves. cf-branch folded into
// wave 3 of phase A (R5); XCD-chunked swizzle (R6); shuffle edges (R7);
// hand-forced MLP (R10: 56.5->48.9us).
// R14: the register-budget bind. gfx950's unified VGPR+AGPR file gives
// 512/3 = 170 regs/wave at 3 waves/SIMD. Demand was ~100 VGPR (A/B peak)
// + 48 AGPR (phase-C acc[12]) -> either spill (R12, 49.2us) or 2 waves/SIMD
// (R13, 55.2us). Shrink demand instead: phase C runs as TWO N-halves of 6
// w-tiles (acc[6] = 24 AGPR, declared per-pass; K-loop intact per pass so
// accumulation is exact). A-frags re-stream per half (36 extra L1-hot
// loads). Pre-A A-frag preload dropped (frees 8 VGPRs across A/B).
// Expect: no spill AND 3 waves/SIMD.
//   A: spatial filters, 8+8 double-buffered load batches + sched_barrier
//   B: wave<->16ch, lane<->4 px; named 6xfloat4 prefetch one pair ahead
//      (iter-0 loads hoisted before A); halo rows branch-free via x{0,1};
//      writes a_T bf16 with XOR-chunk swizzle
//   C: 1x9 conv as bf16 MFMA GEMM M=64 x N=192 x K=576; two passes of 6
//      w-tiles; A-frags via rolling 3-reg window, distance-2 prefetch
// ---------------------------------------------------------------------------
__global__ __launch_bounds__(256, 3) void k_main(const float* __restrict__ x,
                                                 const float* __restrict__ sw,
                                                 const float* __restrict__ sb,
                                                 const float* __restrict__ partials,
                                                 const float* __restrict__ cw1,
                                                 const float* __restrict__ cb1,
                                                 const float* __restrict__ cw2,
                                                 const float* __restrict__ cb2,
                                                 const unsigned short* __restrict__ w2bf,
                                                 const float* __restrict__ bias2,
                                                 float* __restrict__ out) {
    __shared__ __align__(16) char smem[38624];
    short*          aT    = (short*)smem;           // 200*72*2 = 28800 B
    unsigned*       aT32  = (unsigned*)smem;
    float*          sw_l  = (float*)smem;           // alias (phase A only), 2304 B
    float*          s_l   = (float*)(smem + 28800); // 4*9*48*4 = 6912 B
    float*          b2_l  = (float*)(smem + 35712); // 256 B
    float*          sb_l  = (float*)(smem + 35968); // 40 B
    float*          cfn_l = (float*)(smem + 36016); // 64*9*4 = 2304 B
    float*          h1_l  = (float*)(smem + 38320); // 48 B
    float*          g_l   = (float*)(smem + 38368); // 256 B

    int bx = blockIdx.x;
    int bh = (bx & 7) * 96 + (bx >> 3);   // XCD-chunked swizzle (768 = 8*96)
    int bb = bh / H_;
    int h  = bh - bb * H_;
    int tid = threadIdx.x;
    int lane = tid & 63, wid = tid >> 6;
    int quad = lane >> 4, l16 = lane & 15;
    int obase = wid * 16;
    int w0 = 4 * lane;                    // phase-B pixel base (lane<48 only)

    // ---- stage small tables ----
    for (int i = tid; i < TAPS_ * C_; i += 256) sw_l[i] = sw[i];
    if (tid < C_) b2_l[tid] = bias2[tid];
    if (tid < TAPS_) sb_l[tid] = sb[tid];
    __syncthreads();

    // A-row pointer for phase C (loads issued there; nothing held across A/B)
    const short* arow = (const short*)w2bf + (obase + l16) * K_TOT + quad * 8;

    // ---- phase-B row offsets (clamped halo; zeroed via rokf scale) ----
    long ro0 = (long)((h > 0) ? (h - 1) : h) * W_;
    long ro1 = (long)h * W_;
    long ro2 = (long)((h < H_ - 1) ? (h + 1) : h) * W_;
    const float* xc = x + (size_t)bb * C_ * HW_;

    // ---- phase-B iteration-0 prologue loads: issued BEFORE phase A so the
    //      L2/HBM latency hides under phase A compute (R10: works; R11 showed
    //      loading them inside B spills B's hot loop instead -- worse). ----
    float4 P0a, P1a, P2a, P0b, P1b, P2b;
    if (lane < 48) {
        const float* q0 = xc + (size_t)(wid * 16) * HW_;
        const float* q1 = q0 + HW_;
        P0a = *(const float4*)(q0 + ro0 + w0);
        P1a = *(const float4*)(q0 + ro1 + w0);
        P2a = *(const float4*)(q0 + ro2 + w0);
        P0b = *(const float4*)(q1 + ro0 + w0);
        P1b = *(const float4*)(q1 + ro1 + w0);
        P2b = *(const float4*)(q1 + ro2 + w0);
    }

    // ---- Phase A: spatial filters (waves 0..2, 8+8 double-buffered loads) ∥
    //      channel branch (wave 3) ----
    if (tid < W_) {
        int w = tid;
        float acc[TAPS_];
        #pragma unroll
        for (int t = 0; t < TAPS_; ++t) acc[t] = sb_l[t];
        const float* px = x + (size_t)bb * C_ * HW_ + h * W_ + w;
        float xv0[8], xv1[8];
        #pragma unroll
        for (int j = 0; j < 8; ++j) xv0[j] = px[(size_t)j * HW_];
        #pragma unroll
        for (int j = 0; j < 8; ++j) xv1[j] = px[(size_t)(8 + j) * HW_];
        __builtin_amdgcn_sched_barrier(0);

#define FMA8(XV, CB)                                                           \
        do {                                                                   \
            _Pragma("unroll")                                                  \
            for (int j = 0; j < 8; ++j)                                        \
                _Pragma("unroll")                                              \
                for (int t = 0; t < TAPS_; ++t)                                \
                    acc[t] = fmaf(XV[j], sw_l[t * C_ + (CB) + j], acc[t]);     \
        } while (0)
#define LOAD8(XV, CB)                                                          \
        do {                                                                   \
            _Pragma("unroll")                                                  \
            for (int j = 0; j < 8; ++j) XV[j] = px[(size_t)((CB) + j) * HW_];  \
        } while (0)

        FMA8(xv0, 0);   LOAD8(xv0, 16); __builtin_amdgcn_sched_barrier(0);
        FMA8(xv1, 8);   LOAD8(xv1, 24); __builtin_amdgcn_sched_barrier(0);
        FMA8(xv0, 16);  LOAD8(xv0, 32); __builtin_amdgcn_sched_barrier(0);
        FMA8(xv1, 24);  LOAD8(xv1, 40); __builtin_amdgcn_sched_barrier(0);
        FMA8(xv0, 32);  LOAD8(xv0, 48); __builtin_amdgcn_sched_barrier(0);
        FMA8(xv1, 40);  LOAD8(xv1, 56); __builtin_amdgcn_sched_barrier(0);
        FMA8(xv0, 48);
        FMA8(xv1, 56);
#undef FMA8
#undef LOAD8

        float mean = 0.f;
        #pragma unroll
        for (int t = 0; t < TAPS_; ++t) mean += acc[t];
        mean *= (1.f / TAPS_);
        float var = 0.f;
        #pragma unroll
        for (int t = 0; t < TAPS_; ++t) { float d = acc[t] - mean; var += d * d; }
        var *= (1.f / (TAPS_ - 1));
        float scale = STD_ / (sqrtf(fmaxf(var, 0.f)) + 1e-10f);
        float* sp = s_l + (w & 3) * 432 + (w >> 2);
        #pragma unroll
        for (int t = 0; t < TAPS_; ++t) sp[t * 48] = (acc[t] - mean) * scale;
    } else {
        // wave 3, lane = channel c. All LDS chains below are same-array
        // write->read in one lockstep wave (compiler orders via lgkmcnt).
        int c = lane;
        const float* pp = partials + (bb * C_ + c) * 3;
        g_l[c] = (pp[0] + pp[1] + pp[2]) * (1.0f / HW_);
        if (c < MID_) {
            float acc = cb1[c];
            #pragma unroll 8
            for (int cc = 0; cc < C_; ++cc) acc += g_l[cc] * cw1[c * C_ + cc];
            h1_l[c] = fmaxf(acc, 0.f);
        }
        float f[TAPS_];
        float mean = 0.f;
        #pragma unroll
        for (int t = 0; t < TAPS_; ++t) {
            int n = c * TAPS_ + t;
            float acc = cb2[n];
            #pragma unroll
            for (int m = 0; m < MID_; ++m) acc += h1_l[m] * cw2[n * MID_ + m];
            f[t] = acc;
            mean += acc;
        }
        mean *= (1.f / TAPS_);
        float var = 0.f;
        #pragma unroll
        for (int t = 0; t < TAPS_; ++t) { float d = f[t] - mean; var += d * d; }
        var *= (1.f / (TAPS_ - 1));
        float scale = STD_ / (sqrtf(fmaxf(var, 0.f)) + 1e-10f);
        #pragma unroll
        for (int t = 0; t < TAPS_; ++t)
            cfn_l[c * TAPS_ + t] = (f[t] - mean) * scale;
    }
    __syncthreads();   // phase B overwrites sw_l alias (aT); reads s_l + cfn_l

    // ---- zero a_T halo rows (0..3 and 196..199); swizzle is a row-local
    //      permutation, so linear zeroing covers exactly the same words ----
    for (int i = tid; i < 8 * (AT_STRIDE / 2); i += 256) {
        int rowIdx = i / (AT_STRIDE / 2);
        int col    = i - rowIdx * (AT_STRIDE / 2);
        int r = (rowIdx < 4) ? rowIdx : (192 + rowIdx);
        aT32[r * (AT_STRIDE / 2) + col] = 0u;
    }

    // ---- Phase B: DDF apply + leaky -> a_T bf16 (swizzled), pipelined ----
    {
        if (lane < 48) {
            float sreg[4][TAPS_];      // conflict-free: word = 432k+48t+lane
            #pragma unroll
            for (int k = 0; k < 4; ++k) {
                const float* sp = s_l + k * 432 + lane;
                #pragma unroll
                for (int t = 0; t < TAPS_; ++t) sreg[k][t] = sp[t * 48];
            }
            bool l0 = (lane == 0), l47 = (lane == 47);
            float rok0f = (h > 0)      ? 1.f : 0.f;
            float rok2f = (h < H_ - 1) ? 1.f : 0.f;

#define TAPROW(RR, FA, FB)                                                     \
            do {                                                               \
                float ma = __shfl_up(FA.w, 1);   ma = l0  ? 0.f : ma;          \
                float mb = __shfl_up(FB.w, 1);   mb = l0  ? 0.f : mb;          \
                float pa = __shfl_down(FA.x, 1); pa = l47 ? 0.f : pa;          \
                float pb = __shfl_down(FB.x, 1); pb = l47 ? 0.f : pb;          \
                float va[6] = { ma, FA.x, FA.y, FA.z, FA.w, pa };              \
                float vb[6] = { mb, FB.x, FB.y, FB.z, FB.w, pb };              \
                _Pragma("unroll")                                              \
                for (int dc = 0; dc < 3; ++dc) {                               \
                    int t = (RR) * 3 + dc;                                     \
                    float cva = cfp[t];                                        \
                    float cvb = cfp[TAPS_ + t];                                \
                    _Pragma("unroll")                                          \
                    for (int k = 0; k < 4; ++k) {                              \
                        acc0[k] = fmaf(va[k + dc] * sreg[k][t], cva, acc0[k]); \
                        acc1[k] = fmaf(vb[k + dc] * sreg[k][t], cvb, acc1[k]); \
                    }                                                          \
                }                                                              \
            } while (0)

            #pragma unroll 1
            for (int i = 0; i < 16; i += 2) {
                int c0 = wid * 16 + i;
                int cu = __builtin_amdgcn_readfirstlane(c0);
                const float* cfp = cfn_l + cu * TAPS_;   // LDS broadcast
                // consume current prefetch
                float4 C0a = P0a, C1a = P1a, C2a = P2a;
                float4 C0b = P0b, C1b = P1b, C2b = P2b;
                // prefetch next channel pair (distance 1)
                if (i < 14) {
                    const float* q0 = xc + (size_t)(c0 + 2) * HW_;
                    const float* q1 = q0 + HW_;
                    P0a = *(const float4*)(q0 + ro0 + w0);
                    P1a = *(const float4*)(q0 + ro1 + w0);
                    P2a = *(const float4*)(q0 + ro2 + w0);
                    P0b = *(const float4*)(q1 + ro0 + w0);
                    P1b = *(const float4*)(q1 + ro1 + w0);
                    P2b = *(const float4*)(q1 + ro2 + w0);
                }
                __builtin_amdgcn_sched_barrier(0);
                // zero halo-row contributions (exact: 0 * finite == 0 == pad)
                C0a.x *= rok0f; C0a.y *= rok0f; C0a.z *= rok0f; C0a.w *= rok0f;
                C0b.x *= rok0f; C0b.y *= rok0f; C0b.z *= rok0f; C0b.w *= rok0f;
                C2a.x *= rok2f; C2a.y *= rok2f; C2a.z *= rok2f; C2a.w *= rok2f;
                C2b.x *= rok2f; C2b.y *= rok2f; C2b.z *= rok2f; C2b.w *= rok2f;
                float acc0[4] = {0.f, 0.f, 0.f, 0.f};
                float acc1[4] = {0.f, 0.f, 0.f, 0.f};
                TAPROW(0, C0a, C0b);
                TAPROW(1, C1a, C1b);
                TAPROW(2, C2a, C2b);
                int cw = c0 >> 1;                  // word col 0..31
                #pragma unroll
                for (int k = 0; k < 4; ++k) {
                    float a0v = acc0[k]; a0v = (a0v >= 0.f) ? a0v : 0.1f * a0v;
                    float a1v = acc1[k]; a1v = (a1v >= 0.f) ? a1v : 0.1f * a1v;
                    unsigned pk = (unsigned)f2bf_bits(a0v)
                                | ((unsigned)f2bf_bits(a1v) << 16);
                    aT32[at_word(w0 + k + 4, cw)] = pk;
                }
            }
#undef TAPROW
        }
    }
    __syncthreads();

    // ---- Phase C: MFMA GEMM out[o][w] += A[o][q] * B[q][w], q = t*64 + c.
    //      Two N-halves of 6 w-tiles: acc[6] = 24 AGPR per pass (fits the
    //      170-reg budget at 3 waves/SIMD). K-loop intact per pass. ----
    {
        size_t xbase = (size_t)bb * C_ * HW_ + (size_t)h * W_;
        #pragma unroll 1
        for (int half = 0; half < 2; ++half) {
            int nbase = half * 6;
            int noff  = nbase * 16 * AT_STRIDE;
            f32x4 acc[6];
            #pragma unroll
            for (int j = 0; j < 6; ++j) acc[j] = (f32x4){0.f, 0.f, 0.f, 0.f};
            short8 a0 = *(const short8*)(arow);
            short8 a1 = *(const short8*)(arow + 32);

            #pragma unroll 1
            for (int kk = 0; kk < 18; ++kk) {
                short8 a2 = a1;
                if (kk < 16) a2 = *(const short8*)(arow + (kk + 2) * 32);  // dist-2 stream
                int t = kk >> 1;
                int ch = ((kk & 1) << 2) + quad;     // 16-B chunk index 0..7
                int rowb = l16 + t;
                int key0 = (rowb >> 2) & 7;          // key(n) = key0 ^ (4*(n&1))
                int off0 = rowb * AT_STRIDE + (((ch ^ key0) & 7) << 3) + noff;
                int off1 = rowb * AT_STRIDE + (((ch ^ key0 ^ 4) & 7) << 3) + noff;
                #pragma unroll
                for (int j = 0; j < 6; ++j) {        // n = nbase + j; n&1 == j&1
                    int off = ((j & 1) ? off1 : off0) + j * 16 * AT_STRIDE;
                    short8 bf = *(const short8*)(aT + off);
                    acc[j] = __builtin_amdgcn_mfma_f32_16x16x32_bf16(a0, bf, acc[j], 0, 0, 0);
                }
                a0 = a1; a1 = a2;
            }

            // epilogue: bias + residual add, C/D layout col=lane&15, row=quad*4+reg
            #pragma unroll
            for (int j = 0; j < 6; ++j) {
                int w = (nbase + j) * 16 + l16;
                #pragma unroll
                for (int reg = 0; reg < 4; ++reg) {
                    int o = obase + quad * 4 + reg;
                    size_t idx = xbase + (size_t)o * HW_ + w;
                    out[idx] = acc[j][reg] + b2_l[o] + x[idx];
                }
            }
        }
    }
}

// ---------------------------------------------------------------------------
extern "C" void kernel_launch(void* const* d_in, const int* in_sizes, int n_in,
                              void* d_out, int out_size, void* d_ws, size_t ws_size,
                              hipStream_t stream) {
    const float* x   = (const float*)d_in[0];
    const float* sw  = (const float*)d_in[1];
    const float* sb  = (const float*)d_in[2];
    const float* cw1 = (const float*)d_in[3];
    const float* cb1 = (const float*)d_in[4];
    const float* cw2 = (const float*)d_in[5];
    const float* cb2 = (const float*)d_in[6];
    const float* w2  = (const float*)d_in[7];
    const float* b2  = (const float*)d_in[8];
    float* out = (float*)d_out;

    unsigned short* w2bf = (unsigned short*)d_ws;                 // 73728 B
    float* partials = (float*)((char*)d_ws + 73728);              // 3072 B

    hipLaunchKernelGGL(k_pre, dim3(912), dim3(256), 0, stream, x, w2, w2bf, partials);
    hipLaunchKernelGGL(k_main, dim3(B_ * H_), dim3(256), 0, stream,
                       x, sw, sb, partials, cw1, cb1, cw2, cb2, w2bf, b2, out);
}